// Round 3
// baseline (112.187 us; speedup 1.0000x reference)
//
#include <hip/hip_runtime.h>
#include <cstddef>

// ---------------------------------------------------------------------------
// JPEG blockwise 8x8 DCT + quantization.
//   image:          [16, 1, 1024, 1024] fp32
//   quality_factor: [16] fp32
//   out:            [16, 64, 128, 128] fp32, channel c = u*8+v
//
// R7: isolate the READ path (the only invariant across the R4/R5/R6 null
// experiments). Previously each lane read its own 8x8 block directly:
// 16 B/lane at 32 B lane-stride = 50% per-instruction density (16 cache
// lines per wave instr). Now: stage each 8-row pixel strip via LDS --
//   - all 256 threads issue 8 fully DENSE float4 loads (lane-consecutive,
//     1 KiB per wave instr),
//   - LDS placement XOR-swizzled (phys = p ^ ((p>>1)&7), bijective/row) so
//     BOTH the staging b128 writes and the strided b128 block-gathers are
//     bank-conflict-free (lane bank-groups all-distinct per 8 lanes),
//   - each thread gathers its 8x8 block from LDS, then DCT/quant/store
//     exactly as R6 (1 KiB-burst cooperative stores).
// Single variable: global-read density 50% -> 100%.
// Roofline: 64 MB in + 64 MB out => ~20.4 us at 6.3 TB/s; VALU ~2 us.
// ---------------------------------------------------------------------------

static constexpr double LUMQ[64] = {
    16, 11, 10, 16, 24, 40, 51, 61,
    12, 12, 14, 19, 26, 58, 60, 55,
    14, 13, 16, 24, 40, 57, 69, 56,
    14, 17, 22, 29, 51, 87, 80, 62,
    18, 22, 37, 56, 68, 109, 103, 77,
    24, 36, 55, 64, 81, 104, 113, 92,
    49, 64, 78, 87, 103, 121, 120, 101,
    72, 92, 95, 98, 112, 100, 103, 99,
};

// AAN per-coefficient scale: sqrt(2)*cos(k*pi/16), k=1..7; 1.0 for k=0.
static constexpr double AANS[8] = {
    1.0, 1.3870398453221475, 1.3065629648763766, 1.1758756024193588,
    1.0, 0.7856949583871022, 0.5411961001461970, 0.2758993792829430,
};

// Reference divides by Q = LUMQ/100; AAN raw 2D output is
// 8*aans[u]*aans[v] times the orthonormal DCT. Fold both (compile-time).
__device__ __host__ __forceinline__ constexpr float outScale(int u, int v) {
    return (float)(100.0 / (LUMQ[u * 8 + v] * 8.0 * AANS[u] * AANS[v]));
}

// AAN 8-point scaled forward DCT (jfdctflt.c flowgraph).
// In-place; output k is the true orthonormal DCT * sqrt(8) * aans[k].
__device__ __forceinline__ void aan_dct8(float& x0, float& x1, float& x2,
                                         float& x3, float& x4, float& x5,
                                         float& x6, float& x7) {
    const float t0 = x0 + x7, t7 = x0 - x7;
    const float t1 = x1 + x6, t6 = x1 - x6;
    const float t2 = x2 + x5, t5 = x2 - x5;
    const float t3 = x3 + x4, t4 = x3 - x4;

    // Even part
    float t10 = t0 + t3;
    const float t13 = t0 - t3;
    const float t11 = t1 + t2;
    const float t12 = t1 - t2;
    x0 = t10 + t11;
    x4 = t10 - t11;
    const float z1 = (t12 + t13) * 0.70710678118654752f;
    x2 = t13 + z1;
    x6 = t13 - z1;

    // Odd part
    t10 = t4 + t5;
    const float u11 = t5 + t6;
    const float u12 = t6 + t7;
    const float z5 = (t10 - u12) * 0.38268343236508977f;
    const float z2 = 0.54119610014619698f * t10 + z5;
    const float z4 = 1.30656296487637653f * u12 + z5;
    const float z3 = u11 * 0.70710678118654752f;
    const float z11 = t7 + z3;
    const float z13 = t7 - z3;
    x5 = z13 + z2;
    x3 = z13 - z2;
    x1 = z11 + z4;
    x7 = z11 - z4;
}

// Stage one 8-row x 1024-col pixel strip (32 KiB) into LDS.
// Thread t handles slot (q*256 + t) for q=0..7: global loads are dense
// (lane-consecutive float4, 1 KiB/wave instr). LDS write position is
// XOR-swizzled: phys = p ^ ((p>>1)&7) -- bank-group (phys&7) is distinct
// across every 8 consecutive lanes -> conflict-free ds_write_b128.
__device__ __forceinline__ void stage_strip(const float* __restrict__ strip,
                                            float* __restrict__ lds, int tid) {
    float4 r[8];
    #pragma unroll
    for (int q = 0; q < 8; ++q)
        r[q] = *reinterpret_cast<const float4*>(strip + (size_t)((q << 8) + tid) * 4);
    const int phys = tid ^ ((tid >> 1) & 7);
    #pragma unroll
    for (int q = 0; q < 8; ++q)
        *reinterpret_cast<float4*>(lds + (q << 10) + (phys << 2)) = r[q];
}

// Gather block jcol from the swizzled strip: row n, cols 8j..8j+7 live in
// original slots 2j (cols 0-3) and 2j+1 (cols 4-7); phys(2j) = 2j ^ (j&7),
// phys(2j+1) = phys(2j) ^ 1. Bank-groups distinct per 8 lanes -> conflict-
// free ds_read_b128.
__device__ __forceinline__ void gather_block(const float* __restrict__ lds,
                                             int jcol, float m[8][8]) {
    const int p0 = (2 * jcol) ^ (jcol & 7);
    #pragma unroll
    for (int n = 0; n < 8; ++n) {
        const float4 lo = *reinterpret_cast<const float4*>(lds + (n << 10) + (p0 << 2));
        const float4 hi = *reinterpret_cast<const float4*>(lds + (n << 10) + ((p0 ^ 1) << 2));
        m[n][0] = lo.x; m[n][1] = lo.y; m[n][2] = lo.z; m[n][3] = lo.w;
        m[n][4] = hi.x; m[n][5] = hi.y; m[n][6] = hi.z; m[n][7] = hi.w;
    }
}

__global__ __launch_bounds__(256) void jpeg_dct_quant_kernel(
    const float* __restrict__ img,   // [16,1,1024,1024]
    const float* __restrict__ qfv,   // [16]
    float* __restrict__ out)         // [16,64,128,128]
{
    __shared__ float lds[8192];      // 32 KiB, reused: strip staging -> out transpose

    const int tid = threadIdx.x;
    const int wg  = blockIdx.x;
    const int a   = tid >> 7;        // which of the WG's two block-rows this thread owns
    const int j   = tid & 127;       // block col
    const int R0  = wg << 1;         // global block-row of strip 0
    const int b   = R0 >> 7;         // batch (uniform within WG)
    const int i0  = R0 & 127;        // local block-row of strip 0 (even)

    const float* stripA = img + ((size_t)b << 20) + (size_t)i0 * 8192;
    const float* stripB = stripA + 8192;

    float m[8][8];

    // Strip A: dense load -> swizzled LDS -> block gather (threads a==0).
    stage_strip(stripA, lds, tid);
    __syncthreads();
    if (a == 0) gather_block(lds, j, m);
    __syncthreads();

    // Strip B.
    stage_strip(stripB, lds, tid);
    __syncthreads();
    if (a == 1) gather_block(lds, j, m);

    // Row pass (along columns within each row).
    #pragma unroll
    for (int n = 0; n < 8; ++n)
        aan_dct8(m[n][0], m[n][1], m[n][2], m[n][3],
                 m[n][4], m[n][5], m[n][6], m[n][7]);

    // Column pass.
    #pragma unroll
    for (int v = 0; v < 8; ++v)
        aan_dct8(m[0][v], m[1][v], m[2][v], m[3][v],
                 m[4][v], m[5][v], m[6][v], m[7][v]);

    // -128 centering only affects the raw DC term: 128*64 = 8192.
    m[0][0] -= 8192.0f;

    const float qf = qfv[b];
    const float factor = (qf < 50.0f) ? (5000.0f / qf) : (200.0f - 2.0f * qf);
    const float invf = 1.0f / factor;

    // Fold quant scale into registers before the LDS transpose.
    #pragma unroll
    for (int u = 0; u < 8; ++u)
        #pragma unroll
        for (int v = 0; v < 8; ++v)
            m[u][v] *= invf * outScale(u, v);

    // Output: same 1 KiB-burst cooperative store path as R6. Rows i0, i0+1
    // of a c-plane are contiguous 1 KiB; each wave stores 8 planes/phase.
    const int w = tid >> 6;          // wave id 0..3
    const int l = tid & 63;          // lane
    float* dstbase = out + ((size_t)b << 20) + (size_t)i0 * 128 + (l << 2);

    #pragma unroll
    for (int phase = 0; phase < 2; ++phase) {
        __syncthreads();             // LDS free (gather B / previous stores done)

        // Write this thread's 32 coeffs with c in [phase*32, phase*32+32).
        // addr = c_local*256 + a*128 + j -> bank = j%32: conflict-free.
        #pragma unroll
        for (int u = phase * 4; u < phase * 4 + 4; ++u)
            #pragma unroll
            for (int v = 0; v < 8; ++v)
                lds[(u * 8 + v - phase * 32) * 256 + a * 128 + j] = m[u][v];
        __syncthreads();

        // Each wave stores 8 planes: one instr = one dense 1 KiB burst
        // (64 lanes x float4 covering rows i0 and i0+1 of plane c).
        #pragma unroll
        for (int k = 0; k < 8; ++k) {
            const int cl = w * 8 + k;            // local plane 0..31
            const int c  = phase * 32 + cl;      // global channel
            *reinterpret_cast<float4*>(dstbase + (size_t)c * 16384) =
                *reinterpret_cast<const float4*>(&lds[cl * 256 + (l << 2)]);
        }
    }
}

extern "C" void kernel_launch(void* const* d_in, const int* in_sizes, int n_in,
                              void* d_out, int out_size, void* d_ws, size_t ws_size,
                              hipStream_t stream) {
    const float* img = (const float*)d_in[0];   // 16*1024*1024 fp32
    const float* qfv = (const float*)d_in[1];   // 16 fp32
    float* out = (float*)d_out;                 // 16*64*128*128 fp32

    // 16*128*128 = 262144 blocks, one thread each; 256 threads/WG -> 1024 WGs.
    jpeg_dct_quant_kernel<<<1024, 256, 0, stream>>>(img, qfv, out);
}